// Round 10
// baseline (70.738 us; speedup 1.0000x reference)
//
#include <hip/hip_runtime.h>
#include <stdint.h>

#define BATCH 999
#define HID 1024
#define SEQ 160

#define BB 64                         // batches per block (4 waves x 16)
#define WB 16                         // batches per wave
#define NBB 16                        // 16 * 64 = 1024 >= 999
#define KS 2                          // k-split
#define KPER (HID / KS)               // 512 k per block
#define HS 16                         // h-split
#define HPER (HID / HS)               // 64 h per block (= 32 h-pairs)
#define NTILE (KS * HS)               // 32 hk-tiles per b-group
#define UTHRESH 40.0f                 // |est| below this -> fp32 refine
#define RKQ 4                         // refine k-split (4 blocks per batch)

// NOTE: __fp16 element type — must match __builtin_amdgcn_cvt_pkrtz's return
// type and __builtin_amdgcn_fdot2's operand type (clang sig: fV2hV2hfIb).
typedef __fp16 half2 __attribute__((ext_vector_type(2)));

#if __has_builtin(__builtin_amdgcn_fdot2)
#define FDOT2(a, b, c) __builtin_amdgcn_fdot2((a), (b), (c), false)
#else  // safety fallback: same math in fp32 (slower, still correct)
static __device__ inline float FDOT2(half2 a, half2 b, float c) {
    return c + (float)a.x * (float)b.x + (float)a.y * (float)b.y;
}
#endif
#define PKRTZ(a, b) __builtin_amdgcn_cvt_pkrtz((a), (b))

// Cross-block state. All of it is either fully overwritten every launch
// (gpart, uflag) or self-restoring (gcnt/ucnt2 wrap mod N; wsdot returns to 0
// after each use). Zero-initialized at module load -> idempotent under replay.
__device__ float    gpart[NTILE][NBB][BB];   // 131 KB estimate partials
__device__ unsigned gcnt[NBB];               // wraps mod 32
__device__ unsigned uflag[1024];             // dense per-batch refine flag
__device__ float    wsdot[1024];             // refine accumulators (0-invariant)
__device__ unsigned ucnt2[1024];             // per-batch refine arrival, mod 4

__global__ __launch_bounds__(256, 2)
void dots_est_kernel(const float* __restrict__ Cg, const float* __restrict__ Rg,
                     const float* __restrict__ Mg, float* __restrict__ out)
{
    __shared__ uint32_t sCp[HPER / 2][BB];   // 8 KB: packed h-pairs of C
    __shared__ float sRed[4][BB];            // 1 KB tail reduction
    __shared__ int sdone;

    const int tid  = threadIdx.x;
    const int lane = tid & 63;
    const int w    = tid >> 6;        // wave id 0..3 -> owns 16 batches

    // XCD-aware bijective decode: per-XCD working set ~3.5 MB < 4 MB L2
    const int L    = blockIdx.x;      // 0..511
    const int xcd  = L & 7;
    const int slot = L >> 3;          // 0..63
    const int tile = xcd * 4 + (slot & 3);   // 0..31
    const int by   = slot >> 2;       // 0..15
    const int kx   = tile >> 4;       // 0..1
    const int hz   = tile & 15;       // 0..15
    const int b0   = by * BB;
    const int k0   = kx * KPER;
    const int h0   = hz * HPER;

    // ---- stage C slice once, packed into f16 h-pairs: sCp[hp][b] ----
    {
        const int b  = tid & 63;
        const int hq = tid >> 6;      // 0..3, 16 consecutive h each
        const int gb = b0 + b;
        float4 v[4];
        #pragma unroll
        for (int q = 0; q < 4; ++q) v[q] = make_float4(0.f, 0.f, 0.f, 0.f);
        if (gb < BATCH) {
            const float* cp = Cg + ((size_t)gb * SEQ + (SEQ - 1)) * HID + h0 + hq * 16;
            #pragma unroll
            for (int q = 0; q < 4; ++q) v[q] = *(const float4*)(cp + 4 * q);
        }
        // pack (h even -> lo, h odd -> hi); bank = b&31 -> 2-way = free
        #pragma unroll
        for (int q = 0; q < 4; ++q) {
            half2 p0 = PKRTZ(v[q].x, v[q].y);
            half2 p1 = PKRTZ(v[q].z, v[q].w);
            sCp[hq * 8 + q * 2 + 0][b] = __builtin_bit_cast(uint32_t, p0);
            sCp[hq * 8 + q * 2 + 1][b] = __builtin_bit_cast(uint32_t, p1);
        }
    }
    __syncthreads();   // the ONLY barrier before the tail

    float4 acc[WB][2]; // fp32 accs: 16 batches x 8 k (k = k0 + lane*4 +{0,256})
    #pragma unroll
    for (int i = 0; i < WB; ++i) {
        acc[i][0] = make_float4(0.f, 0.f, 0.f, 0.f);
        acc[i][1] = make_float4(0.f, 0.f, 0.f, 0.f);
    }

    // M streamed from global (L2-resident), rows packed to f16 h-pairs in-reg,
    // one-pair lookahead, NO barriers, NO LDS for M.
    const float* mbase = Mg + (size_t)h0 * HID + k0 + (lane << 2);

    auto fmahp = [&](int hp, float4 a0, float4 b0v, float4 a1, float4 b1v) {
        // pack M h-pair: (row 2hp -> lo, row 2hp+1 -> hi), 8 k-columns
        half2 mp0 = PKRTZ(a0.x, a1.x), mp1 = PKRTZ(a0.y, a1.y);
        half2 mp2 = PKRTZ(a0.z, a1.z), mp3 = PKRTZ(a0.w, a1.w);
        half2 mp4 = PKRTZ(b0v.x, b1v.x), mp5 = PKRTZ(b0v.y, b1v.y);
        half2 mp6 = PKRTZ(b0v.z, b1v.z), mp7 = PKRTZ(b0v.w, b1v.w);
        // wave-uniform broadcast reads: this wave's 16 packed C pairs (64B)
        const uint4* cr = (const uint4*)&sCp[hp][w << 4];
        const uint4 cu0 = cr[0], cu1 = cr[1], cu2 = cr[2], cu3 = cr[3];
        const uint32_t cs_u[WB] = {cu0.x, cu0.y, cu0.z, cu0.w,
                                   cu1.x, cu1.y, cu1.z, cu1.w,
                                   cu2.x, cu2.y, cu2.z, cu2.w,
                                   cu3.x, cu3.y, cu3.z, cu3.w};
        #pragma unroll
        for (int i = 0; i < WB; ++i) {
            const half2 ch = __builtin_bit_cast(half2, cs_u[i]);
            acc[i][0].x = FDOT2(ch, mp0, acc[i][0].x);
            acc[i][0].y = FDOT2(ch, mp1, acc[i][0].y);
            acc[i][0].z = FDOT2(ch, mp2, acc[i][0].z);
            acc[i][0].w = FDOT2(ch, mp3, acc[i][0].w);
            acc[i][1].x = FDOT2(ch, mp4, acc[i][1].x);
            acc[i][1].y = FDOT2(ch, mp5, acc[i][1].y);
            acc[i][1].z = FDOT2(ch, mp6, acc[i][1].z);
            acc[i][1].w = FDOT2(ch, mp7, acc[i][1].w);
        }
    };

    float4 m0a = *(const float4*)(mbase);
    float4 m0b = *(const float4*)(mbase + 256);
    float4 m1a = *(const float4*)(mbase + HID);
    float4 m1b = *(const float4*)(mbase + HID + 256);

    for (int hp = 0; hp < HPER / 2 - 1; ++hp) {
        const float* nb = mbase + ((size_t)(2 * hp + 2) << 10);
        float4 n0a = *(const float4*)(nb);
        float4 n0b = *(const float4*)(nb + 256);
        float4 n1a = *(const float4*)(nb + HID);
        float4 n1b = *(const float4*)(nb + HID + 256);
        fmahp(hp, m0a, m0b, m1a, m1b);
        m0a = n0a; m0b = n0b; m1a = n1a; m1b = n1b;
    }
    fmahp(HPER / 2 - 1, m0a, m0b, m1a, m1b);

    // ---- epilogue: fp32 dot with R row-slice, butterfly, partial store ----
    #pragma unroll
    for (int i = 0; i < WB; ++i) {
        const int gb = b0 + w * WB + i;
        float p = 0.f;
        if (gb < BATCH) {
            const float* rp = Rg + ((size_t)gb * SEQ + (SEQ - 1)) * HID + k0 + (lane << 2);
            const float4 r0 = *(const float4*)(rp);
            const float4 r1 = *(const float4*)(rp + 256);
            p = acc[i][0].x * r0.x + acc[i][0].y * r0.y + acc[i][0].z * r0.z + acc[i][0].w * r0.w
              + acc[i][1].x * r1.x + acc[i][1].y * r1.y + acc[i][1].z * r1.z + acc[i][1].w * r1.w;
        }
        #pragma unroll
        for (int m = 1; m < 64; m <<= 1) p += __shfl_xor(p, m, 64);
        if (lane == 0)
            __hip_atomic_store(&gpart[tile][by][w * WB + i], p,
                               __ATOMIC_RELAXED, __HIP_MEMORY_SCOPE_AGENT);
    }

    // ---- completion protocol (proven R4-R7): drain -> counter ----
    asm volatile("s_waitcnt vmcnt(0)" ::: "memory");
    __syncthreads();
    if (tid == 0) {
        unsigned old = __hip_atomic_fetch_add(&gcnt[by], 1u,
                                              __ATOMIC_RELAXED, __HIP_MEMORY_SCOPE_AGENT);
        sdone = ((old & (NTILE - 1)) == (NTILE - 1));
    }
    __syncthreads();

    // ---- fused tail: reduce estimate, sigmoid, write dense refine flags ----
    if (sdone) {
        const int b = tid & 63;
        const int q = tid >> 6;       // 0..3 -> 8 tiles each
        float s = 0.f;
        #pragma unroll
        for (int t = 0; t < 8; ++t)
            s += __hip_atomic_load(&gpart[q * 8 + t][by][b],
                                   __ATOMIC_RELAXED, __HIP_MEMORY_SCOPE_AGENT);
        sRed[q][b] = s;
        __syncthreads();
        if (tid < BB) {
            const int gb = b0 + tid;
            if (gb < BATCH) {
                float d = sRed[0][tid] + sRed[1][tid] + sRed[2][tid] + sRed[3][tid];
                out[gb] = 1.f / (1.f + __expf(-d));
                // flag is fully overwritten (0 or 1) every launch: stateless
                __hip_atomic_store(&uflag[gb], (fabsf(d) < UTHRESH) ? 1u : 0u,
                                   __ATOMIC_RELAXED, __HIP_MEMORY_SCOPE_AGENT);
            }
        }
    }
}

// Exact fp32 recompute of flagged batches. 4 blocks per batch (k-quarters);
// unflagged blocks exit after one load. Combination uses the same proven
// last-arrival protocol; wsdot returns to 0 after each use (replay-safe).
__global__ __launch_bounds__(256)
void refine_kernel(const float* __restrict__ Cg, const float* __restrict__ Rg,
                   const float* __restrict__ Mg, float* __restrict__ out)
{
    __shared__ float sred[4];
    const int tid  = threadIdx.x;
    const int lane = tid & 63;
    const int w    = tid >> 6;        // h-strip 0..3 (256 rows each)

    const int b  = blockIdx.x >> 2;   // 0..1023 (>=999 never flagged)
    const int kq = blockIdx.x & 3;    // k-quarter

    // uniform broadcast load of the flag (same address all threads)
    if (!__hip_atomic_load(&uflag[b], __ATOMIC_RELAXED, __HIP_MEMORY_SCOPE_AGENT))
        return;

    const int c0 = kq * 256 + ((tid & 63) << 2);   // this thread's 4 k-cols
    const float* crow = Cg + ((size_t)b * SEQ + (SEQ - 1)) * HID;
    const float* mcol = Mg + c0;
    float4 acc = make_float4(0.f, 0.f, 0.f, 0.f);

    for (int i = 0; i < 256; i += 2) {            // h-strip w: rows w*256+i
        const int h = (w << 8) + i;
        const float  ca = crow[h];                // uniform scalar broadcasts
        const float  cb = crow[h + 1];
        const float4 r0 = *(const float4*)(mcol + ((size_t)h << 10));
        const float4 r1 = *(const float4*)(mcol + ((size_t)(h + 1) << 10));
        acc.x += ca * r0.x + cb * r1.x;
        acc.y += ca * r0.y + cb * r1.y;
        acc.z += ca * r0.z + cb * r1.z;
        acc.w += ca * r0.w + cb * r1.w;
    }

    const float4 rv = *(const float4*)(
        Rg + ((size_t)b * SEQ + (SEQ - 1)) * HID + c0);
    float p = acc.x * rv.x + acc.y * rv.y + acc.z * rv.z + acc.w * rv.w;
    #pragma unroll
    for (int m = 1; m < 64; m <<= 1) p += __shfl_xor(p, m, 64);
    if (lane == 0) sred[w] = p;
    __syncthreads();

    if (tid == 0) {
        const float part = sred[0] + sred[1] + sred[2] + sred[3];
        __hip_atomic_fetch_add(&wsdot[b], part,
                               __ATOMIC_RELAXED, __HIP_MEMORY_SCOPE_AGENT);
        asm volatile("s_waitcnt vmcnt(0)" ::: "memory");
        unsigned old = __hip_atomic_fetch_add(&ucnt2[b], 1u,
                                              __ATOMIC_RELAXED, __HIP_MEMORY_SCOPE_AGENT);
        if ((old & (RKQ - 1)) == (RKQ - 1)) {     // last of the 4 k-quarters
            float d = __hip_atomic_load(&wsdot[b],
                                        __ATOMIC_RELAXED, __HIP_MEMORY_SCOPE_AGENT);
            out[b] = 1.f / (1.f + __expf(-d));
            __hip_atomic_store(&wsdot[b], 0.f,    // restore 0-invariant
                               __ATOMIC_RELAXED, __HIP_MEMORY_SCOPE_AGENT);
        }
    }
}

extern "C" void kernel_launch(void* const* d_in, const int* in_sizes, int n_in,
                              void* d_out, int out_size, void* d_ws, size_t ws_size,
                              hipStream_t stream) {
    const float* ctx = (const float*)d_in[0];
    const float* rsp = (const float*)d_in[1];
    const float* M   = (const float*)d_in[2];
    float* out = (float*)d_out;
    (void)d_ws; (void)ws_size;

    dim3 grid(NBB * NTILE);   // 512 blocks, 1-D XCD-aware decode, 2/CU
    dots_est_kernel<<<grid, 256, 0, stream>>>(ctx, rsp, M, out);
    refine_kernel<<<1024 * RKQ, 256, 0, stream>>>(ctx, rsp, M, out);
}

// Round 11
// 41.206 us; speedup vs baseline: 1.7167x; 1.7167x over previous
//
#include <hip/hip_runtime.h>

#define BATCH 999
#define HID 1024
#define SEQ 160

#define BB 64                         // batches per block (4 waves x 16)
#define WB 16                         // batches per wave
#define NBB 16                        // 16 * 64 = 1024 >= 999
#define KS 2                          // k-split
#define KPER (HID / KS)               // 512 k per block
#define HS 16                         // h-split
#define HPER (HID / HS)               // 64 h per block
#define NTILE (KS * HS)               // 32 hk-tiles per b-group

// Cross-block staging (device-coherent access only; zero-init not required:
// every slot is written each launch before it is read).
__device__ float gpart[NTILE][NBB][BB];     // 131 KB
__device__ unsigned gcnt[NBB];              // wraps mod 32 each launch: no reset

__global__ __launch_bounds__(256, 2)
void dots_kernel(const float* __restrict__ Cg, const float* __restrict__ Rg,
                 const float* __restrict__ Mg, float* __restrict__ out)
{
    __shared__ float sC[HPER][BB];    // 16 KB, C transposed: sC[h][b]
    __shared__ float sRed[4][BB];     // 1 KB, tail reduction
    __shared__ int sdone;

    const int tid  = threadIdx.x;
    const int lane = tid & 63;
    const int w    = tid >> 6;        // wave id 0..3 -> owns 16 batches

    // XCD-aware bijective decode: per-XCD working set ~3.5 MB < 4 MB L2
    const int L    = blockIdx.x;      // 0..511
    const int xcd  = L & 7;
    const int slot = L >> 3;          // 0..63
    const int tile = xcd * 4 + (slot & 3);   // 0..31
    const int by   = slot >> 2;       // 0..15
    const int kx   = tile >> 4;       // 0..1
    const int hz   = tile & 15;       // 0..15
    const int b0   = by * BB;
    const int k0   = kx * KPER;
    const int h0   = hz * HPER;

    // ---- stage C slice once: sC[h][b] = C[b0+b][last, h0+h] ----
    {
        const int b  = tid & 63;
        const int hq = tid >> 6;      // 0..3, 16 h-values each
        const int gb = b0 + b;
        float4 v[4];
        #pragma unroll
        for (int q = 0; q < 4; ++q) v[q] = make_float4(0.f, 0.f, 0.f, 0.f);
        if (gb < BATCH) {
            const float* cp = Cg + ((size_t)gb * SEQ + (SEQ - 1)) * HID + h0 + hq * 16;
            #pragma unroll
            for (int q = 0; q < 4; ++q) v[q] = *(const float4*)(cp + 4 * q);
        }
        // bank = b&31 -> 2-way wave64 aliasing = free
        #pragma unroll
        for (int q = 0; q < 4; ++q) {
            sC[hq * 16 + q * 4 + 0][b] = v[q].x;
            sC[hq * 16 + q * 4 + 1][b] = v[q].y;
            sC[hq * 16 + q * 4 + 2][b] = v[q].z;
            sC[hq * 16 + q * 4 + 3][b] = v[q].w;
        }
    }
    __syncthreads();

    float4 acc[WB][2]; // 16 batches x 8 k-floats
    #pragma unroll
    for (int i = 0; i < WB; ++i) {
        acc[i][0] = make_float4(0.f, 0.f, 0.f, 0.f);
        acc[i][1] = make_float4(0.f, 0.f, 0.f, 0.f);
    }

    // M rows straight from global (L1/L2-resident, coalesced 16B/lane),
    // two-row register prefetch, NO barriers, NO LDS for M.
    const float* mbase = Mg + (size_t)h0 * HID + k0 + (lane << 2);

    auto fmah = [&](int h, float4 ma, float4 mb) {
        const float* crow = &sC[h][w << 4];
        const float4 c0 = *(const float4*)(crow);       // wave-uniform broadcasts
        const float4 c1 = *(const float4*)(crow + 4);
        const float4 c2 = *(const float4*)(crow + 8);
        const float4 c3 = *(const float4*)(crow + 12);
        const float cs[WB] = {c0.x, c0.y, c0.z, c0.w, c1.x, c1.y, c1.z, c1.w,
                              c2.x, c2.y, c2.z, c2.w, c3.x, c3.y, c3.z, c3.w};
        #pragma unroll
        for (int i = 0; i < WB; ++i) {
            acc[i][0].x += cs[i] * ma.x; acc[i][0].y += cs[i] * ma.y;
            acc[i][0].z += cs[i] * ma.z; acc[i][0].w += cs[i] * ma.w;
            acc[i][1].x += cs[i] * mb.x; acc[i][1].y += cs[i] * mb.y;
            acc[i][1].z += cs[i] * mb.z; acc[i][1].w += cs[i] * mb.w;
        }
    };

    float4 m0a = *(const float4*)(mbase);
    float4 m0b = *(const float4*)(mbase + 256);
    float4 m1a = *(const float4*)(mbase + HID);
    float4 m1b = *(const float4*)(mbase + HID + 256);

    for (int h = 0; h < HPER - 2; h += 2) {
        const float* nb = mbase + (size_t)(h + 2) * HID;
        float4 n0a = *(const float4*)(nb);
        float4 n0b = *(const float4*)(nb + 256);
        float4 n1a = *(const float4*)(nb + HID);
        float4 n1b = *(const float4*)(nb + HID + 256);
        fmah(h, m0a, m0b);
        fmah(h + 1, m1a, m1b);
        m0a = n0a; m0b = n0b; m1a = n1a; m1b = n1b;
    }
    fmah(HPER - 2, m0a, m0b);
    fmah(HPER - 1, m1a, m1b);

    // ---- epilogue: dot with R row-slice, butterfly, coherent partial store ----
    #pragma unroll
    for (int i = 0; i < WB; ++i) {
        const int gb = b0 + w * WB + i;
        float p = 0.f;
        if (gb < BATCH) {
            const float* rp = Rg + ((size_t)gb * SEQ + (SEQ - 1)) * HID + k0 + (lane << 2);
            const float4 r0 = *(const float4*)(rp);
            const float4 r1 = *(const float4*)(rp + 256);
            p = acc[i][0].x * r0.x + acc[i][0].y * r0.y + acc[i][0].z * r0.z + acc[i][0].w * r0.w
              + acc[i][1].x * r1.x + acc[i][1].y * r1.y + acc[i][1].z * r1.z + acc[i][1].w * r1.w;
        }
        #pragma unroll
        for (int m = 1; m < 64; m <<= 1) p += __shfl_xor(p, m, 64);
        if (lane == 0)
            __hip_atomic_store(&gpart[tile][by][w * WB + i], p,
                               __ATOMIC_RELAXED, __HIP_MEMORY_SCOPE_AGENT);
    }

    // ---- completion protocol: drain stores to coherence point -> counter ----
    asm volatile("s_waitcnt vmcnt(0)" ::: "memory");
    __syncthreads();
    if (tid == 0) {
        unsigned old = __hip_atomic_fetch_add(&gcnt[by], 1u,
                                              __ATOMIC_RELAXED, __HIP_MEMORY_SCOPE_AGENT);
        sdone = ((old & (NTILE - 1)) == (NTILE - 1));
    }
    __syncthreads();

    // ---- fused tail: last-arrival block reduces 32 partials + sigmoid ----
    if (sdone) {
        const int b = tid & 63;
        const int q = tid >> 6;       // 0..3 -> 8 tiles each
        float s = 0.f;
        #pragma unroll
        for (int t = 0; t < 8; ++t)
            s += __hip_atomic_load(&gpart[q * 8 + t][by][b],
                                   __ATOMIC_RELAXED, __HIP_MEMORY_SCOPE_AGENT);
        sRed[q][b] = s;
        __syncthreads();
        if (tid < BB) {
            const int gb = b0 + tid;
            if (gb < BATCH) {
                float d = sRed[0][tid] + sRed[1][tid] + sRed[2][tid] + sRed[3][tid];
                out[gb] = 1.f / (1.f + __expf(-d));
            }
        }
    }
}

extern "C" void kernel_launch(void* const* d_in, const int* in_sizes, int n_in,
                              void* d_out, int out_size, void* d_ws, size_t ws_size,
                              hipStream_t stream) {
    const float* ctx = (const float*)d_in[0];
    const float* rsp = (const float*)d_in[1];
    const float* M   = (const float*)d_in[2];
    float* out = (float*)d_out;
    (void)d_ws; (void)ws_size;

    dim3 grid(NBB * NTILE);   // 512 blocks, 1-D XCD-aware decode, 2/CU
    dots_kernel<<<grid, 256, 0, stream>>>(ctx, rsp, M, out);
}